// Round 4
// baseline (74.906 us; speedup 1.0000x reference)
//
#include <hip/hip_runtime.h>
#include <hip/hip_bf16.h>
#include <stdint.h>

// Problem constants (fixed by the reference)
#define B_SZ 8192
#define D_SZ 256
#define R_SZ 8
#define N_SZ 1024
#define C_SZ (B_SZ / R_SZ)          // 1024
#define CN   (C_SZ * N_SZ)          // 1048576
#define L_SZ (B_SZ + 2 * R_SZ * CN) // 16785408 (logits length)
#define BD   (B_SZ * D_SZ)          // 2097152 elems per ws array

typedef short bf16x8 __attribute__((ext_vector_type(8)));
typedef float f32x4  __attribute__((ext_vector_type(4)));

static __device__ __forceinline__ unsigned short f2bf(float f) {
  unsigned u = __float_as_uint(f);
  u += 0x7FFFu + ((u >> 16) & 1u);   // RNE
  return (unsigned short)(u >> 16);
}
static __device__ __forceinline__ float bf2f(unsigned short h) {
  return __uint_as_float(((unsigned)h) << 16);
}
static __device__ __forceinline__ float sigmoidf_(float x) {
  return 1.0f / (1.0f + __expf(-x));
}
static __device__ __forceinline__ void gload16(const void* g, void* l) {
  __builtin_amdgcn_global_load_lds(
      (const __attribute__((address_space(1))) void*)g,
      (__attribute__((address_space(3))) void*)l, 16, 0, 0);
}

// ws layout (bytes):
//   0        : lhs_hi_s (4MB)   sorted by relation: row p = r*1024 + c
//   4MB      : lhs_lo_s
//   8MB      : rhs_hi_s
//   12MB     : rhs_lo_s
//   16MB     : inv (32KB int)   inv[order[j]] = j
//   16MB+64K : Bp_hi (8MB)      packed sampled panels, row j = (side*8+r)*1024+n
//   24MB+64K : Bp_lo (8MB)

// ---------------------------------------------------------------------------
__global__ void inv_kernel(const int* __restrict__ order, int* __restrict__ inv) {
  int j = blockIdx.x * 256 + threadIdx.x;
  inv[order[j]] = j;
}

// ---------------------------------------------------------------------------
// Phase 1: F-reduce emb -> lhs/rhs, split bf16 hi+lo, SCATTER to sorted rows.
// One wave per batch row i. 2048 blocks x 256 threads. (~9 us, BW-bound.)
// ---------------------------------------------------------------------------
__global__ __launch_bounds__(256) void prep_kernel(
    const float* __restrict__ emb, const float* __restrict__ trans,
    const int* __restrict__ rels, const int* __restrict__ inv,
    float* __restrict__ out, unsigned short* __restrict__ sortArr) {
  unsigned short* lhs_hi = sortArr;
  unsigned short* lhs_lo = sortArr + (size_t)BD;
  unsigned short* rhs_hi = sortArr + (size_t)2 * BD;
  unsigned short* rhs_lo = sortArr + (size_t)3 * BD;

  int wave = threadIdx.x >> 6;
  int lane = threadIdx.x & 63;
  int i = blockIdx.x * 4 + wave;            // 0..B-1

  const float4* emb4 = (const float4*)emb;  // emb row j = 128 float4 (F*D=512 f32)
  size_t bl = (size_t)(2 * i) * 128;
  size_t br = (size_t)(2 * i + 1) * 128;
  float4 a0 = emb4[bl + lane];
  float4 a1 = emb4[bl + 64 + lane];
  float4 b0 = emb4[br + lane];
  float4 b1 = emb4[br + 64 + lane];
  float lh[4] = {a0.x + a1.x, a0.y + a1.y, a0.z + a1.z, a0.w + a1.w};
  float rh[4] = {b0.x + b1.x, b0.y + b1.y, b0.z + b1.z, b0.w + b1.w};

  int rel = rels[i];
  float4 tv = ((const float4*)trans)[rel * 64 + lane];
  float tt[4] = {tv.x, tv.y, tv.z, tv.w};

  float p = 0.f;
#pragma unroll
  for (int j = 0; j < 4; ++j) p += lh[j] * (rh[j] + tt[j]);
#pragma unroll
  for (int off = 32; off; off >>= 1) p += __shfl_xor(p, off, 64);
  if (lane == 0) {
    out[i] = p;
    out[(size_t)L_SZ + i] = sigmoidf_(p);
  }

  int sp = inv[i];  // sorted row
  unsigned short h[4], l[4];
#pragma unroll
  for (int j = 0; j < 4; ++j) {
    h[j] = f2bf(lh[j]);
    l[j] = f2bf(lh[j] - bf2f(h[j]));
  }
  *(ushort4*)(lhs_hi + (size_t)sp * 256 + lane * 4) = make_ushort4(h[0], h[1], h[2], h[3]);
  *(ushort4*)(lhs_lo + (size_t)sp * 256 + lane * 4) = make_ushort4(l[0], l[1], l[2], l[3]);
#pragma unroll
  for (int j = 0; j < 4; ++j) {
    h[j] = f2bf(rh[j]);
    l[j] = f2bf(rh[j] - bf2f(h[j]));
  }
  *(ushort4*)(rhs_hi + (size_t)sp * 256 + lane * 4) = make_ushort4(h[0], h[1], h[2], h[3]);
  *(ushort4*)(rhs_lo + (size_t)sp * 256 + lane * 4) = make_ushort4(l[0], l[1], l[2], l[3]);
}

// ---------------------------------------------------------------------------
// Pack sampled B-panels contiguous: row j=(side*8+r)*1024+n <- sorted row
// inv[neg[r,n]] of lhs (side0) / rhs (side1). Gathers are latency-tolerant
// here (2048 independent blocks). ~32MB traffic, ~6 us.
// ---------------------------------------------------------------------------
__global__ __launch_bounds__(256) void pack_kernel(
    const unsigned short* __restrict__ sortArr, const int* __restrict__ inv,
    const int* __restrict__ negL, const int* __restrict__ negR,
    unsigned short* __restrict__ bp) {
  int t = threadIdx.x;
  int j = blockIdx.x * 8 + (t >> 5);      // 0..16383
  int side = j >> 13, rr = (j >> 10) & 7, n = j & 1023;
  const int* negp = side ? negR : negL;
  int src = inv[negp[rr * N_SZ + n]];     // sorted row 0..8191
  const unsigned short* sHi = sortArr + (side ? (size_t)2 * BD : 0) + (size_t)src * 256;
  const unsigned short* sLo = sHi + (size_t)BD;
  unsigned short* dHi = bp + (size_t)j * 256;
  unsigned short* dLo = dHi + (size_t)16384 * 256;
  int c = (t & 31) * 8;
  *(int4*)(dHi + c) = *(const int4*)(sHi + c);
  *(int4*)(dLo + c) = *(const int4*)(sLo + c);
}

// ---------------------------------------------------------------------------
// Phase 2: negatives GEMM, now with fully CONTIGUOUS staging. 128x128 tile,
// 4 waves (2x2), 1024 blocks (2/CU), BK=64, single-buffer 64KB LDS, R1-proven
// 2-barrier schedule (compiler-managed waits). Wave w stages array w
// (Ah/Al/Bh/Bl, 16KB each) with 16x global_load_lds w=16. XOR swizzle
// (chunk ^ row&7) on source + ds_read -> conflict-free b128 reads.
// Split-bf16: acc += Ah*Bh + Al*Bh + Ah*Bl. XCD swizzle: relation r per XCD.
// ---------------------------------------------------------------------------
template <bool PB>
__global__ __launch_bounds__(256, 2) void negs_kernel(
    const unsigned short* __restrict__ ws, const int* __restrict__ inv,
    const unsigned short* __restrict__ bp,
    const int* __restrict__ negL, const int* __restrict__ negR,
    float* __restrict__ out) {
  __shared__ char lds[4][16384];  // Ah, Al, Bh, Bl ; rows of 128B (BK=64)

  const char* base0 = (const char*)ws;

  int hw = blockIdx.x;
  int bid = (hw & 7) * 128 + (hw >> 3);   // bijective: r == XCD
  int ntile = bid & 7;
  int ctile = (bid >> 3) & 7;
  int side  = (bid >> 6) & 1;
  int r     = bid >> 7;

  int t = threadIdx.x;
  int wave = t >> 6, lane = t & 63;
  int wrow = wave >> 1, wcol = wave & 1;
  int lrow = lane >> 3;                       // 0..7
  unsigned laneswz = (unsigned)((lane & 7) ^ lrow) << 4;

  // side 0: A = s_rhs, B = samp_lhs ; side 1: A = s_lhs, B = samp_rhs
  const char* srcp;
  unsigned goff[16];
  if (wave < 2) {
    size_t arr = (side ? (size_t)0 : (size_t)4 * BD) + (wave == 1 ? (size_t)2 * BD : 0);
    srcp = base0 + arr;                       // bytes: hi@0/8MB, lo@4MB/12MB
    int rb = r * C_SZ + ctile * 128 + lrow;
#pragma unroll
    for (int it = 0; it < 16; ++it) goff[it] = (unsigned)(rb + it * 8) * 512u + laneswz;
  } else if (PB) {
    srcp = (const char*)bp + (wave == 3 ? (size_t)16384 * 512 : 0);
    int rb = (side * 8 + r) * 1024 + ntile * 128 + lrow;
#pragma unroll
    for (int it = 0; it < 16; ++it) goff[it] = (unsigned)(rb + it * 8) * 512u + laneswz;
  } else {
    size_t arr = (side ? (size_t)4 * BD : (size_t)0) + (wave == 3 ? (size_t)2 * BD : 0);
    srcp = base0 + arr;
    const int* negp = side ? negR : negL;
    int nb = r * N_SZ + ntile * 128 + lrow;
#pragma unroll
    for (int it = 0; it < 16; ++it)
      goff[it] = (unsigned)inv[negp[nb + it * 8]] * 512u + laneswz;
  }
  char* myLds = &lds[wave][0];

  f32x4 acc[4][4] = {};
  int lx = lane & 15;

#pragma unroll 1
  for (int kc = 0; kc < 4; ++kc) {
#pragma unroll
    for (int it = 0; it < 16; ++it)
      gload16(srcp + goff[it] + (unsigned)kc * 128u, myLds + it * 1024);
    __syncthreads();

#pragma unroll
    for (int ks = 0; ks < 2; ++ks) {
      int q = ks * 4 + (lane >> 4);                 // logical 16B chunk 0..7
      bf16x8 ah[4], al_[4], bh[4], bl_[4];
#pragma unroll
      for (int mi = 0; mi < 4; ++mi) {
        int row = wrow * 64 + mi * 16 + lx;
        int off = row * 128 + ((q ^ (row & 7)) << 4);
        ah[mi]  = *(const bf16x8*)(&lds[0][0] + off);
        al_[mi] = *(const bf16x8*)(&lds[1][0] + off);
      }
#pragma unroll
      for (int ni = 0; ni < 4; ++ni) {
        int row = wcol * 64 + ni * 16 + lx;
        int off = row * 128 + ((q ^ (row & 7)) << 4);
        bh[ni]  = *(const bf16x8*)(&lds[2][0] + off);
        bl_[ni] = *(const bf16x8*)(&lds[3][0] + off);
      }
#pragma unroll
      for (int mi = 0; mi < 4; ++mi)
#pragma unroll
        for (int ni = 0; ni < 4; ++ni) {
          acc[mi][ni] = __builtin_amdgcn_mfma_f32_16x16x32_bf16(ah[mi],  bh[ni],  acc[mi][ni], 0, 0, 0);
          acc[mi][ni] = __builtin_amdgcn_mfma_f32_16x16x32_bf16(al_[mi], bh[ni],  acc[mi][ni], 0, 0, 0);
          acc[mi][ni] = __builtin_amdgcn_mfma_f32_16x16x32_bf16(ah[mi],  bl_[ni], acc[mi][ni], 0, 0, 0);
        }
    }
    __syncthreads();
  }

  // Epilogue: C/D layout col = lane&15 (n dim), row = (lane>>4)*4 + j (c dim).
  size_t obase = (size_t)B_SZ + ((size_t)(r * 2 + side)) * CN;
  int gcb = ntile * 128 + wcol * 64 + lx;
  int grb = ctile * 128 + wrow * 64 + ((lane >> 4) << 2);
#pragma unroll
  for (int mi = 0; mi < 4; ++mi) {
#pragma unroll
    for (int ni = 0; ni < 4; ++ni) {
      int gc = gcb + ni * 16;
#pragma unroll
      for (int j = 0; j < 4; ++j) {
        int gr = grb + mi * 16 + j;
        size_t idx = obase + (size_t)gr * N_SZ + gc;
        float v = acc[mi][ni][j];
        __builtin_nontemporal_store(v, &out[idx]);
        __builtin_nontemporal_store(sigmoidf_(v), &out[(size_t)L_SZ + idx]);
      }
    }
  }
}

// ---------------------------------------------------------------------------
extern "C" void kernel_launch(void* const* d_in, const int* in_sizes, int n_in,
                              void* d_out, int out_size, void* d_ws, size_t ws_size,
                              hipStream_t stream) {
  const float* emb   = (const float*)d_in[0];
  const float* trans = (const float*)d_in[1];
  const int*   rels  = (const int*)d_in[2];
  const int*   order = (const int*)d_in[3];
  const int*   negL  = (const int*)d_in[4];
  const int*   negR  = (const int*)d_in[5];
  float* out = (float*)d_out;

  unsigned short* sortArr = (unsigned short*)d_ws;
  int* inv = (int*)((char*)d_ws + (size_t)16 * 1024 * 1024);
  unsigned short* bp = (unsigned short*)((char*)d_ws + (size_t)16 * 1024 * 1024 + 65536);
  bool packed = ws_size >= (size_t)32 * 1024 * 1024 + 65536;

  inv_kernel<<<32, 256, 0, stream>>>(order, inv);
  prep_kernel<<<B_SZ / 4, 256, 0, stream>>>(emb, trans, rels, inv, out, sortArr);
  if (packed) {
    pack_kernel<<<2048, 256, 0, stream>>>(sortArr, inv, negL, negR, bp);
    negs_kernel<true><<<1024, 256, 0, stream>>>(sortArr, inv, bp, negL, negR, out);
  } else {
    negs_kernel<false><<<1024, 256, 0, stream>>>(sortArr, inv, bp, negL, negR, out);
  }
}

// Round 5
// 74.403 us; speedup vs baseline: 1.0068x; 1.0068x over previous
//
#include <hip/hip_runtime.h>
#include <hip/hip_bf16.h>
#include <stdint.h>

// Problem constants (fixed by the reference)
#define B_SZ 8192
#define D_SZ 256
#define R_SZ 8
#define N_SZ 1024
#define C_SZ (B_SZ / R_SZ)          // 1024
#define CN   (C_SZ * N_SZ)          // 1048576
#define L_SZ (B_SZ + 2 * R_SZ * CN) // 16785408 (logits length)
#define BD   (B_SZ * D_SZ)          // 2097152 elems per ws array

typedef short bf16x8 __attribute__((ext_vector_type(8)));
typedef float f32x4  __attribute__((ext_vector_type(4)));

static __device__ __forceinline__ unsigned short f2bf(float f) {
  unsigned u = __float_as_uint(f);
  u += 0x7FFFu + ((u >> 16) & 1u);   // RNE
  return (unsigned short)(u >> 16);
}
static __device__ __forceinline__ float bf2f(unsigned short h) {
  return __uint_as_float(((unsigned)h) << 16);
}
static __device__ __forceinline__ float sigmoidf_(float x) {
  return 1.0f / (1.0f + __expf(-x));
}
static __device__ __forceinline__ void gload16(const void* g, void* l) {
  __builtin_amdgcn_global_load_lds(
      (const __attribute__((address_space(1))) void*)g,
      (__attribute__((address_space(3))) void*)l, 16, 0, 0);
}

// ws layout (bytes):
//   0        : lhs_hi_s (4MB)   sorted by relation: row p = r*1024 + c
//   4MB      : lhs_lo_s
//   8MB      : rhs_hi_s
//   12MB     : rhs_lo_s
//   16MB     : inv (32KB int)   inv[order[j]] = j

// ---------------------------------------------------------------------------
__global__ void inv_kernel(const int* __restrict__ order, int* __restrict__ inv) {
  int j = blockIdx.x * 256 + threadIdx.x;
  inv[order[j]] = j;
}

// ---------------------------------------------------------------------------
// Phase 1: F-reduce emb -> lhs/rhs, split bf16 hi+lo, SCATTER to sorted rows.
// One wave per batch row i. 2048 blocks x 256 threads. (~9 us, BW-bound.)
// ---------------------------------------------------------------------------
__global__ __launch_bounds__(256) void prep_kernel(
    const float* __restrict__ emb, const float* __restrict__ trans,
    const int* __restrict__ rels, const int* __restrict__ inv,
    float* __restrict__ out, unsigned short* __restrict__ sortArr) {
  unsigned short* lhs_hi = sortArr;
  unsigned short* lhs_lo = sortArr + (size_t)BD;
  unsigned short* rhs_hi = sortArr + (size_t)2 * BD;
  unsigned short* rhs_lo = sortArr + (size_t)3 * BD;

  int wave = threadIdx.x >> 6;
  int lane = threadIdx.x & 63;
  int i = blockIdx.x * 4 + wave;            // 0..B-1

  const float4* emb4 = (const float4*)emb;  // emb row j = 128 float4 (F*D=512 f32)
  size_t bl = (size_t)(2 * i) * 128;
  size_t br = (size_t)(2 * i + 1) * 128;
  float4 a0 = emb4[bl + lane];
  float4 a1 = emb4[bl + 64 + lane];
  float4 b0 = emb4[br + lane];
  float4 b1 = emb4[br + 64 + lane];
  float lh[4] = {a0.x + a1.x, a0.y + a1.y, a0.z + a1.z, a0.w + a1.w};
  float rh[4] = {b0.x + b1.x, b0.y + b1.y, b0.z + b1.z, b0.w + b1.w};

  int rel = rels[i];
  float4 tv = ((const float4*)trans)[rel * 64 + lane];
  float tt[4] = {tv.x, tv.y, tv.z, tv.w};

  float p = 0.f;
#pragma unroll
  for (int j = 0; j < 4; ++j) p += lh[j] * (rh[j] + tt[j]);
#pragma unroll
  for (int off = 32; off; off >>= 1) p += __shfl_xor(p, off, 64);
  if (lane == 0) {
    out[i] = p;
    out[(size_t)L_SZ + i] = sigmoidf_(p);
  }

  int sp = inv[i];  // sorted row
  unsigned short h[4], l[4];
#pragma unroll
  for (int j = 0; j < 4; ++j) {
    h[j] = f2bf(lh[j]);
    l[j] = f2bf(lh[j] - bf2f(h[j]));
  }
  *(ushort4*)(lhs_hi + (size_t)sp * 256 + lane * 4) = make_ushort4(h[0], h[1], h[2], h[3]);
  *(ushort4*)(lhs_lo + (size_t)sp * 256 + lane * 4) = make_ushort4(l[0], l[1], l[2], l[3]);
#pragma unroll
  for (int j = 0; j < 4; ++j) {
    h[j] = f2bf(rh[j]);
    l[j] = f2bf(rh[j] - bf2f(h[j]));
  }
  *(ushort4*)(rhs_hi + (size_t)sp * 256 + lane * 4) = make_ushort4(h[0], h[1], h[2], h[3]);
  *(ushort4*)(rhs_lo + (size_t)sp * 256 + lane * 4) = make_ushort4(l[0], l[1], l[2], l[3]);
}

// ---------------------------------------------------------------------------
// Phase 2: negatives GEMM. 128x128 tile, 4 waves (2x2), 1024 blocks, BK=32,
// single-buffer 32 KB LDS -> 4 blocks/CU (16 waves/CU) for cross-block overlap
// of the 2-barrier schedule (m97 regime). Wave w stages array w (Ah/Al/Bh/Bl,
// 8 KB each, 8x global_load_lds w=16). LDS rows = 64 B (4 chunks); swizzle
// chunk q ^= ((row>>1)&3) on source + read -> <=2-way (free).
// Split-bf16: acc += Ah*Bh + Al*Bh + Ah*Bl. XCD swizzle: relation r per XCD.
// ---------------------------------------------------------------------------
__global__ __launch_bounds__(256, 4) void negs_kernel(
    const unsigned short* __restrict__ ws, const int* __restrict__ inv,
    const int* __restrict__ negL, const int* __restrict__ negR,
    float* __restrict__ out) {
  __shared__ char lds[4][8192];  // Ah, Al, Bh, Bl ; 128 rows x 64 B

  const char* base0 = (const char*)ws;

  int hw = blockIdx.x;
  int bid = (hw & 7) * 128 + (hw >> 3);   // bijective: r == XCD
  int ntile = bid & 7;
  int ctile = (bid >> 3) & 7;
  int side  = (bid >> 6) & 1;
  int r     = bid >> 7;

  int t = threadIdx.x;
  int wave = t >> 6, lane = t & 63;
  int wrow = wave >> 1, wcol = wave & 1;

  // Stage mapping: load 'it' covers rows it*16..it*16+15; lane -> row
  // it*16 + (lane>>2), chunk lane&3. Source chunk inverse-swizzled:
  // (lane&3) ^ ((row>>1)&3) = (lane&3) ^ ((lane>>3)&3)  (it*16 even in bit1+).
  unsigned srcswz = (unsigned)(((lane & 3) ^ ((lane >> 3) & 3)) << 4);

  // side 0: A = s_rhs, B = samp_lhs ; side 1: A = s_lhs, B = samp_rhs
  const char* srcp;
  unsigned goff[8];
  if (wave < 2) {
    size_t arr = (side ? (size_t)0 : (size_t)8 * 1024 * 1024) +
                 (wave == 1 ? (size_t)4 * 1024 * 1024 : 0);
    srcp = base0 + arr;
    int rb = r * C_SZ + ctile * 128 + (lane >> 2);
#pragma unroll
    for (int it = 0; it < 8; ++it)
      goff[it] = (unsigned)(rb + it * 16) * 512u + srcswz;
  } else {
    size_t arr = (side ? (size_t)8 * 1024 * 1024 : (size_t)0) +
                 (wave == 3 ? (size_t)4 * 1024 * 1024 : 0);
    srcp = base0 + arr;
    const int* negp = side ? negR : negL;
    int nb = r * N_SZ + ntile * 128 + (lane >> 2);
#pragma unroll
    for (int it = 0; it < 8; ++it)
      goff[it] = (unsigned)inv[negp[nb + it * 16]] * 512u + srcswz;
  }
  char* myLds = &lds[wave][0];

  f32x4 acc[4][4] = {};
  int lx = lane & 15;
  int q = lane >> 4;  // 16B chunk 0..3 within 64B row

#pragma unroll 1
  for (int kc = 0; kc < 8; ++kc) {
#pragma unroll
    for (int it = 0; it < 8; ++it)
      gload16(srcp + goff[it] + (unsigned)kc * 64u, myLds + it * 1024);
    __syncthreads();

    bf16x8 ah[4], al_[4], bh[4], bl_[4];
#pragma unroll
    for (int mi = 0; mi < 4; ++mi) {
      int row = wrow * 64 + mi * 16 + lx;
      int off = row * 64 + ((q ^ ((row >> 1) & 3)) << 4);
      ah[mi]  = *(const bf16x8*)(&lds[0][0] + off);
      al_[mi] = *(const bf16x8*)(&lds[1][0] + off);
    }
#pragma unroll
    for (int ni = 0; ni < 4; ++ni) {
      int row = wcol * 64 + ni * 16 + lx;
      int off = row * 64 + ((q ^ ((row >> 1) & 3)) << 4);
      bh[ni]  = *(const bf16x8*)(&lds[2][0] + off);
      bl_[ni] = *(const bf16x8*)(&lds[3][0] + off);
    }
#pragma unroll
    for (int mi = 0; mi < 4; ++mi)
#pragma unroll
      for (int ni = 0; ni < 4; ++ni) {
        acc[mi][ni] = __builtin_amdgcn_mfma_f32_16x16x32_bf16(ah[mi],  bh[ni],  acc[mi][ni], 0, 0, 0);
        acc[mi][ni] = __builtin_amdgcn_mfma_f32_16x16x32_bf16(al_[mi], bh[ni],  acc[mi][ni], 0, 0, 0);
        acc[mi][ni] = __builtin_amdgcn_mfma_f32_16x16x32_bf16(ah[mi],  bl_[ni], acc[mi][ni], 0, 0, 0);
      }
    __syncthreads();
  }

  // Epilogue: C/D layout col = lane&15 (n dim), row = (lane>>4)*4 + j (c dim).
  size_t obase = (size_t)B_SZ + ((size_t)(r * 2 + side)) * CN;
  int gcb = ntile * 128 + wcol * 64 + lx;
  int grb = ctile * 128 + wrow * 64 + ((lane >> 4) << 2);
#pragma unroll
  for (int mi = 0; mi < 4; ++mi) {
#pragma unroll
    for (int ni = 0; ni < 4; ++ni) {
      int gc = gcb + ni * 16;
#pragma unroll
      for (int j = 0; j < 4; ++j) {
        int gr = grb + mi * 16 + j;
        size_t idx = obase + (size_t)gr * N_SZ + gc;
        float v = acc[mi][ni][j];
        __builtin_nontemporal_store(v, &out[idx]);
        __builtin_nontemporal_store(sigmoidf_(v), &out[(size_t)L_SZ + idx]);
      }
    }
  }
}

// ---------------------------------------------------------------------------
extern "C" void kernel_launch(void* const* d_in, const int* in_sizes, int n_in,
                              void* d_out, int out_size, void* d_ws, size_t ws_size,
                              hipStream_t stream) {
  const float* emb   = (const float*)d_in[0];
  const float* trans = (const float*)d_in[1];
  const int*   rels  = (const int*)d_in[2];
  const int*   order = (const int*)d_in[3];
  const int*   negL  = (const int*)d_in[4];
  const int*   negR  = (const int*)d_in[5];
  float* out = (float*)d_out;

  unsigned short* sortArr = (unsigned short*)d_ws;
  int* inv = (int*)((char*)d_ws + (size_t)16 * 1024 * 1024);

  inv_kernel<<<32, 256, 0, stream>>>(order, inv);
  prep_kernel<<<B_SZ / 4, 256, 0, stream>>>(emb, trans, rels, inv, out, sortArr);
  negs_kernel<<<1024, 256, 0, stream>>>(sortArr, inv, negL, negR, out);
}